// Round 14
// baseline (433.607 us; speedup 1.0000x reference)
//
#include <hip/hip_runtime.h>
#include <hip/hip_cooperative_groups.h>
#include <cmath>

namespace cg = cooperative_groups;

// CXLoss pipeline, revision 32: ONE cooperative kernel (phases separated by
// grid.sync) + R31 fallback. R31 = 171.8us best; kernel time sums to ~147us
// -> ~25us is inter-dispatch gaps over 6 launches. Fuse: mean -> prep x2 ->
// gA -> gB -> gC(atomicMax) -> final, byte-identical phase bodies, shared
// memory union-aliased (43KB), grid 512 = 2 blocks/CU co-resident. If
// cooperative launch errors (capture unsupported), fall back to the proven
// 6-launch R31 path in the same call.

#define NB 4
#define CC 256
#define HW 4096
#define NQ0 8    // p-slab loop-split (CMAX/WSUM partials)

static constexpr float kEPS = 1e-8f;
static constexpr float kSIG = 0.1f + 1e-8f;

typedef __attribute__((ext_vector_type(8)))  short short8;
typedef __attribute__((ext_vector_type(16))) float f32x16;

// workspace layout (float units)
enum {
  OFF_MEAN = 0,                        // 256 channel means
  OFF_CMAX = 256,                      // NQ0*NB*HW colmax partials
  OFF_WSUM = OFF_CMAX + NQ0*NB*HW,     // NQ0*NB*HW Wsum partials
  OFF_MAXV = OFF_WSUM + NQ0*NB*HW,     // NB*HW maxv (ENCODED uint, atomicMax)
  OFF_GT   = OFF_MAXV + NB*HW,         // NB*HW*CC bf16, fragment-tiled
  OFF_GI   = OFF_GT + NB*HW*CC/2,
  WS_FLOATS_FULL = OFF_GI + NB*HW*CC/2
};

static constexpr unsigned kEncNegInf = 0x007fffffu;  // enc(-inf)

__device__ __forceinline__ unsigned enc_f32(float f) {
  const unsigned u = __float_as_uint(f);
  return (u & 0x80000000u) ? ~u : (u | 0x80000000u);
}
__device__ __forceinline__ float dec_f32(unsigned e) {
  const unsigned u = (e & 0x80000000u) ? (e & 0x7fffffffu) : ~e;
  return __uint_as_float(u);
}

__device__ __forceinline__ ushort cvt_bf16(float x) {
  unsigned u = __float_as_uint(x);
  unsigned r = (u + 0x7fffu + ((u >> 16) & 1u)) >> 16;  // round-nearest-even
  return (ushort)r;
}

__device__ __forceinline__ void glds16(const ushort* g, ushort* l) {
  __builtin_amdgcn_global_load_lds(
      (const __attribute__((address_space(1))) unsigned*)g,
      (__attribute__((address_space(3))) unsigned*)l, 16, 0, 0);
}
__device__ __forceinline__ void s_bar()  { asm volatile("s_barrier" ::: "memory"); }
__device__ __forceinline__ void w_vm4()  { asm volatile("s_waitcnt vmcnt(4)" ::: "memory"); }
__device__ __forceinline__ void w_vm0()  { asm volatile("s_waitcnt vmcnt(0)" ::: "memory"); }
__device__ __forceinline__ void w_lgkm() { asm volatile("s_waitcnt lgkmcnt(0)" ::: "memory"); }

__device__ __forceinline__ float blockSum256(float v) {
  __shared__ float sh[4];
  const int lane = threadIdx.x & 63, wv = threadIdx.x >> 6;
  #pragma unroll
  for (int o = 32; o > 0; o >>= 1) v += __shfl_down(v, o, 64);
  __syncthreads();
  if (lane == 0) sh[wv] = v;
  __syncthreads();
  return sh[0] + sh[1] + sh[2] + sh[3];
}

// ===================== fused cooperative kernel =====================
// grid = 512 blocks x 256 threads, 2 blocks/CU co-resident.
// smem union: prep needs 34048B; sweeps need <=43008B (gC). Use 43008B.
__global__ __launch_bounds__(256, 2) void k_all(
    const float* __restrict__ fT, const float* __restrict__ fI,
    float* __restrict__ ws, float* __restrict__ out)
{
  __shared__ __align__(16) char smem[43008];
  cg::grid_group gg = cg::this_grid();

  const int t = threadIdx.x, l = t & 63;
  const int w = t >> 6, ln31 = l & 31, lhi = l >> 5;
  const int L = blockIdx.x;

  // ---- Phase 1: channel means (blocks 0..255) + MAXV init (blocks 0..63) --
  if (L < 256) {
    const int c = L;
    float s = 0.f;
    for (int n = 0; n < NB; ++n) {
      const float* p = fT + (size_t)(n*CC + c)*HW;
      #pragma unroll
      for (int k = 0; k < 16; ++k) s += p[k*256 + t];
    }
    const float tot = blockSum256(s);
    if (t == 0) ws[OFF_MEAN + c] = tot * (1.0f/16384.0f);
  }
  if (L < 64)
    ((unsigned*)(ws + OFF_MAXV))[L*256 + t] = kEncNegInf;
  gg.sync();

  // ---- Phase 2: prep (2 virtual blocks per real block: T then I) ----
  {
    float* stage = (float*)smem;              // [32][257]
    float* prt   = (float*)(smem + 32896);    // [8][32]
    float* sinv  = (float*)(smem + 33920);    // [32]
    const float* __restrict__ mean = ws + OFF_MEAN;
    for (int rep = 0; rep < 2; ++rep) {
      __syncthreads();                        // stage reuse guard
      int bid = L + rep*512;
      const int tensor = (bid >= 512); bid &= 511;
      const int n = bid >> 7, r32 = bid & 127, p0 = r32*32;
      const float* __restrict__ src = tensor ? fI : fT;
      ushort* __restrict__ dst = (ushort*)(ws + (tensor ? OFF_GI : OFF_GT));
      const int pl = t & 31, cgp = t >> 5;
      float acc = 0.f;
      #pragma unroll
      for (int i = 0; i < 32; ++i) {
        const int c = cgp*32 + i;
        const float v = src[((size_t)(n*CC + c))*HW + p0 + pl] - mean[c];
        stage[pl*257 + c] = v;
        acc += v*v;
      }
      prt[cgp*32 + pl] = acc;
      __syncthreads();
      if (t < 32) {
        float s2 = 0.f;
        #pragma unroll
        for (int g2 = 0; g2 < 8; ++g2) s2 += prt[g2*32 + t];
        sinv[t] = 1.0f/(sqrtf(s2) + kEPS);
      }
      __syncthreads();
      const float iv = sinv[ln31];
      #pragma unroll
      for (int i = 0; i < 4; ++i) {
        const int kc = w*4 + i;
        const int cb = kc*16 + lhi*8;
        short8 o;
        #pragma unroll
        for (int j = 0; j < 8; ++j)
          ((ushort*)&o)[j] = cvt_bf16(stage[ln31*257 + cb + j] * iv);
        *(short8*)(dst + (((size_t)(n*128 + r32)*16 + kc) << 9) + l*8) = o;
      }
    }
  }
  gg.sync();

  // ---- shared sweep geometry ----
  const ushort* __restrict__ gA = (const ushort*)(ws + OFF_GT);
  const ushort* __restrict__ gB = (const ushort*)(ws + OFF_GI);
  const int xcd = L & 7, grp = L >> 3;
  const int nh = xcd*4 + (grp & 3);
  const int cs = grp >> 2;
  const int n = nh >> 3, h = nh & 7;
  const int col0 = cs * 256;
  const ushort* __restrict__ gAn = gA + ((size_t)(n*128 + h*16) << 13);

  // ---- Phase 3: gA sweep (colmax partials) ----
  {
    ushort* Ab   = (ushort*)smem;             // [2][8192]
    float*  red2 = (float*)(smem + 32768);    // [256]

    #pragma unroll
    for (int i = 0; i < 4; ++i)
      glds16(gAn + (size_t)(i*256 + t)*8, Ab + (i*256 + t)*8);
    #pragma unroll
    for (int i = 0; i < 4; ++i)
      glds16(gAn + 8192 + (size_t)(i*256 + t)*8, Ab + 8192 + (i*256 + t)*8);

    short8 breg0[16], breg1[16];
    {
      const int RB0 = cs*8 + w, RB1 = cs*8 + 4 + w;
      #pragma unroll
      for (int kc = 0; kc < 16; ++kc) {
        breg0[kc] = *(const short8*)(gB + (((size_t)(n*128 + RB0)*16 + kc) << 9) + l*8);
        breg1[kc] = *(const short8*)(gB + (((size_t)(n*128 + RB1)*16 + kc) << 9) + l*8);
      }
    }

    float run0 = -3.0e38f, run1 = -3.0e38f;

    for (int iter = 0; iter < 16; ++iter) {
      if (iter < 15) w_vm4(); else w_vm0();
      s_bar();

      const ushort* __restrict__ Abuf = Ab + (iter & 1)*8192;
      f32x16 acc0, acc1;
      #pragma unroll
      for (int e = 0; e < 16; ++e) { acc0[e] = 0.f; acc1[e] = 0.f; }
      #pragma unroll
      for (int kc = 0; kc < 16; ++kc) {
        const short8 a0 = *(const short8*)&Abuf[kc*512 + l*8];
        acc0 = __builtin_amdgcn_mfma_f32_32x32x16_bf16(a0, breg0[kc], acc0, 0, 0, 0);
        acc1 = __builtin_amdgcn_mfma_f32_32x32x16_bf16(a0, breg1[kc], acc1, 0, 0, 0);
      }
      w_lgkm();
      s_bar();
      if (iter + 2 < 16) {
        const ushort* __restrict__ src = gAn + (size_t)(iter + 2)*8192;
        ushort* __restrict__ dstl = Ab + (iter & 1)*8192;
        #pragma unroll
        for (int i = 0; i < 4; ++i)
          glds16(src + (size_t)(i*256 + t)*8, dstl + (i*256 + t)*8);
      }

      #pragma unroll
      for (int r = 0; r < 16; ++r) {
        run0 = fmaxf(run0, acc0[r]);
        run1 = fmaxf(run1, acc1[r]);
      }
    }

    run0 = fmaxf(run0, __shfl_xor(run0, 32, 64));
    run1 = fmaxf(run1, __shfl_xor(run1, 32, 64));
    if (l < 32) {
      red2[w*32 + ln31]       = run0;
      red2[128 + w*32 + ln31] = run1;
    }
    __syncthreads();
    ws[OFF_CMAX + h*(NB*HW) + n*HW + col0 + t] = red2[t];
  }
  gg.sync();

  // ---- Phase 4: gB sweep (Wsum partials) ----
  {
    ushort* Ab   = (ushort*)smem;
    float*  red2 = (float*)(smem + 32768);

    #pragma unroll
    for (int i = 0; i < 4; ++i)
      glds16(gAn + (size_t)(i*256 + t)*8, Ab + (i*256 + t)*8);
    #pragma unroll
    for (int i = 0; i < 4; ++i)
      glds16(gAn + 8192 + (size_t)(i*256 + t)*8, Ab + 8192 + (i*256 + t)*8);

    float aq0, bq0, aq1, bq1;
    {
      const int q0 = col0 + w*32 + ln31;
      const int q1 = q0 + 128;
      float cm0 = -3.0e38f, cm1 = -3.0e38f;
      #pragma unroll
      for (int hh = 0; hh < NQ0; ++hh) {
        cm0 = fmaxf(cm0, ws[OFF_CMAX + hh*(NB*HW) + n*HW + q0]);
        cm1 = fmaxf(cm1, ws[OFF_CMAX + hh*(NB*HW) + n*HW + q1]);
      }
      const float i0 = 1.0f/(2.0f*(0.5f*(1.0f - cm0) + kEPS));
      const float i1 = 1.0f/(2.0f*(0.5f*(1.0f - cm1) + kEPS));
      bq0 = i0 / kSIG; aq0 = (1.0f - i0) / kSIG;
      bq1 = i1 / kSIG; aq1 = (1.0f - i1) / kSIG;
    }

    short8 breg0[16], breg1[16];
    {
      const int RB0 = cs*8 + w, RB1 = cs*8 + 4 + w;
      #pragma unroll
      for (int kc = 0; kc < 16; ++kc) {
        breg0[kc] = *(const short8*)(gB + (((size_t)(n*128 + RB0)*16 + kc) << 9) + l*8);
        breg1[kc] = *(const short8*)(gB + (((size_t)(n*128 + RB1)*16 + kc) << 9) + l*8);
      }
    }

    float ws0 = 0.f, ws1 = 0.f;

    for (int iter = 0; iter < 16; ++iter) {
      if (iter < 15) w_vm4(); else w_vm0();
      s_bar();

      const ushort* __restrict__ Abuf = Ab + (iter & 1)*8192;
      f32x16 acc0, acc1;
      #pragma unroll
      for (int e = 0; e < 16; ++e) { acc0[e] = 0.f; acc1[e] = 0.f; }
      #pragma unroll
      for (int kc = 0; kc < 16; ++kc) {
        const short8 a0 = *(const short8*)&Abuf[kc*512 + l*8];
        acc0 = __builtin_amdgcn_mfma_f32_32x32x16_bf16(a0, breg0[kc], acc0, 0, 0, 0);
        acc1 = __builtin_amdgcn_mfma_f32_32x32x16_bf16(a0, breg1[kc], acc1, 0, 0, 0);
      }
      w_lgkm();
      s_bar();
      if (iter + 2 < 16) {
        const ushort* __restrict__ src = gAn + (size_t)(iter + 2)*8192;
        ushort* __restrict__ dstl = Ab + (iter & 1)*8192;
        #pragma unroll
        for (int i = 0; i < 4; ++i)
          glds16(src + (size_t)(i*256 + t)*8, dstl + (i*256 + t)*8);
      }

      #pragma unroll
      for (int r = 0; r < 16; ++r) {
        ws0 += __expf(fmaf(bq0, acc0[r], aq0));
        ws1 += __expf(fmaf(bq1, acc1[r], aq1));
      }
    }

    ws0 += __shfl_xor(ws0, 32, 64);
    ws1 += __shfl_xor(ws1, 32, 64);
    if (l < 32) {
      red2[w*32 + ln31]       = ws0;
      red2[128 + w*32 + ln31] = ws1;
    }
    __syncthreads();
    ws[OFF_WSUM + h*(NB*HW) + n*HW + col0 + t] = red2[t];
  }
  gg.sync();

  // ---- Phase 5: gC sweep (row-max via swapped operands + atomicMax) ----
  {
    ushort* Ab    = (ushort*)smem;            // [2][8192]
    float*  gam_s = (float*)(smem + 32768);   // [256]
    float*  bet_s = (float*)(smem + 33792);   // [256]
    float*  stash = (float*)(smem + 34816);   // [4][512]

    #pragma unroll
    for (int i = 0; i < 4; ++i)
      glds16(gAn + (size_t)(i*256 + t)*8, Ab + (i*256 + t)*8);
    #pragma unroll
    for (int i = 0; i < 4; ++i)
      glds16(gAn + 8192 + (size_t)(i*256 + t)*8, Ab + 8192 + (i*256 + t)*8);

    // gamma/beta table (formula/order == old k_gb9)
    {
      const int idx = n*HW + col0 + t;
      float cm = -3.0e38f;
      #pragma unroll
      for (int hh = 0; hh < NQ0; ++hh)
        cm = fmaxf(cm, ws[OFF_CMAX + hh*(NB*HW) + idx]);
      float sw = 0.f;
      #pragma unroll
      for (int hh = 0; hh < NQ0; ++hh)
        sw += ws[OFF_WSUM + hh*(NB*HW) + idx];
      const float i0 = 1.0f/(2.0f*(0.5f*(1.0f - cm) + kEPS));
      bet_s[t] = i0 / kSIG;
      gam_s[t] = (1.0f - i0) / kSIG - logf(sw + kEPS);
    }

    short8 breg0[16], breg1[16];
    {
      const int RB0 = cs*8 + w, RB1 = cs*8 + 4 + w;
      #pragma unroll
      for (int kc = 0; kc < 16; ++kc) {
        breg0[kc] = *(const short8*)(gB + (((size_t)(n*128 + RB0)*16 + kc) << 9) + l*8);
        breg1[kc] = *(const short8*)(gB + (((size_t)(n*128 + RB1)*16 + kc) << 9) + l*8);
      }
    }
    __syncthreads();   // gam/bet table ready

    for (int iter = 0; iter < 16; ++iter) {
      if (iter < 15) w_vm4(); else w_vm0();
      s_bar();

      const ushort* __restrict__ Abuf = Ab + (iter & 1)*8192;
      f32x16 accq0, accq1;                    // rows = q, cols = p (swapped)
      #pragma unroll
      for (int e = 0; e < 16; ++e) { accq0[e] = 0.f; accq1[e] = 0.f; }
      #pragma unroll
      for (int kc = 0; kc < 16; ++kc) {
        const short8 a0 = *(const short8*)&Abuf[kc*512 + l*8];
        accq0 = __builtin_amdgcn_mfma_f32_32x32x16_bf16(breg0[kc], a0, accq0, 0, 0, 0);
        accq1 = __builtin_amdgcn_mfma_f32_32x32x16_bf16(breg1[kc], a0, accq1, 0, 0, 0);
      }
      w_lgkm();
      s_bar();
      if (iter + 2 < 16) {
        const ushort* __restrict__ src = gAn + (size_t)(iter + 2)*8192;
        ushort* __restrict__ dstl = Ab + (iter & 1)*8192;
        #pragma unroll
        for (int i = 0; i < 4; ++i)
          glds16(src + (size_t)(i*256 + t)*8, dstl + (i*256 + t)*8);
      }

      float m = -3.0e38f;
      #pragma unroll
      for (int r = 0; r < 16; ++r) {
        const int row = (r & 3) + 8*(r >> 2) + 4*lhi;
        const float g0v = gam_s[w*32 + row],       b0v = bet_s[w*32 + row];
        const float g1v = gam_s[128 + w*32 + row], b1v = bet_s[128 + w*32 + row];
        m = fmaxf(m, fmaf(b0v, accq0[r], g0v));
        m = fmaxf(m, fmaf(b1v, accq1[r], g1v));
      }
      m = fmaxf(m, __shfl_xor(m, 32, 64));
      if (l < 32) stash[w*512 + iter*32 + ln31] = m;
    }

    __syncthreads();
    unsigned* __restrict__ MV = (unsigned*)(ws + OFF_MAXV) + n*HW + h*512;
    #pragma unroll
    for (int p = t; p < 512; p += 256) {
      const float m = fmaxf(fmaxf(stash[0*512 + p], stash[1*512 + p]),
                            fmaxf(stash[2*512 + p], stash[3*512 + p]));
      atomicMax(&MV[p], enc_f32(m));
    }
  }
  gg.sync();

  // ---- Phase 6: final loss (block 0) ----
  if (L == 0) {
    const unsigned* __restrict__ MV = (const unsigned*)(ws + OFF_MAXV);
    float loss = 0.f;
    for (int nn = 0; nn < NB; ++nn) {
      float s = 0.f;
      for (int k = 0; k < 16; ++k)
        s += __expf(dec_f32(MV[nn*HW + k*256 + t]));
      const float tot = blockSum256(s);
      loss += -logf(tot*(1.0f/4096.0f) + kEPS);
    }
    if (t == 0) out[0] = loss*0.25f;
  }
}

// ===================== R31 fallback kernels (proven 171.8us) ==============

__global__ __launch_bounds__(256) void k_mean9(const float* __restrict__ fT,
                                               float* __restrict__ ws) {
  const int c = blockIdx.x, t = threadIdx.x;
  float s = 0.f;
  for (int n = 0; n < NB; ++n) {
    const float* p = fT + (size_t)(n*CC + c)*HW;
    #pragma unroll
    for (int k = 0; k < 16; ++k) s += p[k*256 + t];
  }
  const float tot = blockSum256(s);
  if (t == 0) ws[OFF_MEAN + c] = tot * (1.0f/16384.0f);
}

__global__ __launch_bounds__(256) void k_prep9(const float* __restrict__ fT,
                                               const float* __restrict__ fI,
                                               float* __restrict__ ws) {
  __shared__ float stage[32][257];
  __shared__ float prt[8][32];
  __shared__ float sinv[32];
  const int t = threadIdx.x, l = t & 63;
  const int obid = blockIdx.x;
  int bid = obid;
  const int tensor = (bid >= 512); bid &= 511;
  const int n   = bid >> 7;
  const int r32 = bid & 127;
  const int p0  = r32 * 32;

  if (obid < 64)
    ((unsigned*)(ws + OFF_MAXV))[obid*256 + t] = kEncNegInf;

  const float* __restrict__ src = tensor ? fI : fT;
  ushort* __restrict__ dst = (ushort*)(ws + (tensor ? OFF_GI : OFF_GT));
  const float* __restrict__ mean = ws + OFF_MEAN;

  const int pl = t & 31, cg = t >> 5;
  float acc = 0.f;
  #pragma unroll
  for (int i = 0; i < 32; ++i) {
    const int c = cg*32 + i;
    const float v = src[((size_t)(n*CC + c))*HW + p0 + pl] - mean[c];
    stage[pl][c] = v;
    acc += v*v;
  }
  prt[cg][pl] = acc;
  __syncthreads();
  if (t < 32) {
    float s = 0.f;
    #pragma unroll
    for (int g = 0; g < 8; ++g) s += prt[g][t];
    sinv[t] = 1.0f/(sqrtf(s) + kEPS);
  }
  __syncthreads();

  const int w = t >> 6, lhi = l >> 5, m = l & 31;
  const float iv = sinv[m];
  #pragma unroll
  for (int i = 0; i < 4; ++i) {
    const int kc = w*4 + i;
    const int cb = kc*16 + lhi*8;
    short8 o;
    #pragma unroll
    for (int j = 0; j < 8; ++j)
      ((ushort*)&o)[j] = cvt_bf16(stage[m][cb + j] * iv);
    *(short8*)(dst + (((size_t)(n*128 + r32)*16 + kc) << 9) + l*8) = o;
  }
}

__global__ __launch_bounds__(256, 2) void k_gA(
    const ushort* __restrict__ gA, const ushort* __restrict__ gB,
    float* __restrict__ ws)
{
  __shared__ ushort Ab[2][8192];
  __shared__ float red2[256];

  const int t = threadIdx.x;
  const int w = t >> 6, l = t & 63;
  const int ln31 = l & 31;

  const int L = blockIdx.x;
  const int xcd = L & 7, g = L >> 3;
  const int nh = xcd*4 + (g & 3);
  const int cs = g >> 2;
  const int n = nh >> 3, h = nh & 7;
  const int col0 = cs * 256;

  const ushort* __restrict__ gAn = gA + ((size_t)(n*128 + h*16) << 13);

  #pragma unroll
  for (int i = 0; i < 4; ++i)
    glds16(gAn + (size_t)(i*256 + t)*8, &Ab[0][(i*256 + t)*8]);
  #pragma unroll
  for (int i = 0; i < 4; ++i)
    glds16(gAn + 8192 + (size_t)(i*256 + t)*8, &Ab[1][(i*256 + t)*8]);

  short8 breg0[16], breg1[16];
  {
    const int RB0 = cs*8 + w, RB1 = cs*8 + 4 + w;
    #pragma unroll
    for (int kc = 0; kc < 16; ++kc) {
      breg0[kc] = *(const short8*)(gB + (((size_t)(n*128 + RB0)*16 + kc) << 9) + l*8);
      breg1[kc] = *(const short8*)(gB + (((size_t)(n*128 + RB1)*16 + kc) << 9) + l*8);
    }
  }

  float run0 = -3.0e38f, run1 = -3.0e38f;

  for (int iter = 0; iter < 16; ++iter) {
    if (iter < 15) w_vm4(); else w_vm0();
    s_bar();

    const ushort* __restrict__ Abuf = &Ab[iter & 1][0];
    f32x16 acc0, acc1;
    #pragma unroll
    for (int e = 0; e < 16; ++e) { acc0[e] = 0.f; acc1[e] = 0.f; }
    #pragma unroll
    for (int kc = 0; kc < 16; ++kc) {
      const short8 a0 = *(const short8*)&Abuf[kc*512 + l*8];
      acc0 = __builtin_amdgcn_mfma_f32_32x32x16_bf16(a0, breg0[kc], acc0, 0, 0, 0);
      acc1 = __builtin_amdgcn_mfma_f32_32x32x16_bf16(a0, breg1[kc], acc1, 0, 0, 0);
    }
    w_lgkm();
    s_bar();
    if (iter + 2 < 16) {
      const ushort* __restrict__ src = gAn + (size_t)(iter + 2)*8192;
      ushort* __restrict__ dstl = &Ab[iter & 1][0];
      #pragma unroll
      for (int i = 0; i < 4; ++i)
        glds16(src + (size_t)(i*256 + t)*8, dstl + (i*256 + t)*8);
    }

    #pragma unroll
    for (int r = 0; r < 16; ++r) {
      run0 = fmaxf(run0, acc0[r]);
      run1 = fmaxf(run1, acc1[r]);
    }
  }

  run0 = fmaxf(run0, __shfl_xor(run0, 32, 64));
  run1 = fmaxf(run1, __shfl_xor(run1, 32, 64));
  if (l < 32) {
    red2[w*32 + ln31]       = run0;
    red2[128 + w*32 + ln31] = run1;
  }
  __syncthreads();
  ws[OFF_CMAX + h*(NB*HW) + n*HW + col0 + t] = red2[t];
}

__global__ __launch_bounds__(256, 2) void k_gB(
    const ushort* __restrict__ gA, const ushort* __restrict__ gB,
    float* __restrict__ ws)
{
  __shared__ ushort Ab[2][8192];
  __shared__ float red2[256];

  const int t = threadIdx.x;
  const int w = t >> 6, l = t & 63;
  const int ln31 = l & 31;

  const int L = blockIdx.x;
  const int xcd = L & 7, g = L >> 3;
  const int nh = xcd*4 + (g & 3);
  const int cs = g >> 2;
  const int n = nh >> 3, h = nh & 7;
  const int col0 = cs * 256;

  const ushort* __restrict__ gAn = gA + ((size_t)(n*128 + h*16) << 13);

  #pragma unroll
  for (int i = 0; i < 4; ++i)
    glds16(gAn + (size_t)(i*256 + t)*8, &Ab[0][(i*256 + t)*8]);
  #pragma unroll
  for (int i = 0; i < 4; ++i)
    glds16(gAn + 8192 + (size_t)(i*256 + t)*8, &Ab[1][(i*256 + t)*8]);

  float aq0, bq0, aq1, bq1;
  {
    const int q0 = col0 + w*32 + ln31;
    const int q1 = q0 + 128;
    float cm0 = -3.0e38f, cm1 = -3.0e38f;
    #pragma unroll
    for (int hh = 0; hh < NQ0; ++hh) {
      cm0 = fmaxf(cm0, ws[OFF_CMAX + hh*(NB*HW) + n*HW + q0]);
      cm1 = fmaxf(cm1, ws[OFF_CMAX + hh*(NB*HW) + n*HW + q1]);
    }
    const float i0 = 1.0f/(2.0f*(0.5f*(1.0f - cm0) + kEPS));
    const float i1 = 1.0f/(2.0f*(0.5f*(1.0f - cm1) + kEPS));
    bq0 = i0 / kSIG; aq0 = (1.0f - i0) / kSIG;
    bq1 = i1 / kSIG; aq1 = (1.0f - i1) / kSIG;
  }

  short8 breg0[16], breg1[16];
  {
    const int RB0 = cs*8 + w, RB1 = cs*8 + 4 + w;
    #pragma unroll
    for (int kc = 0; kc < 16; ++kc) {
      breg0[kc] = *(const short8*)(gB + (((size_t)(n*128 + RB0)*16 + kc) << 9) + l*8);
      breg1[kc] = *(const short8*)(gB + (((size_t)(n*128 + RB1)*16 + kc) << 9) + l*8);
    }
  }

  float ws0 = 0.f, ws1 = 0.f;

  for (int iter = 0; iter < 16; ++iter) {
    if (iter < 15) w_vm4(); else w_vm0();
    s_bar();

    const ushort* __restrict__ Abuf = &Ab[iter & 1][0];
    f32x16 acc0, acc1;
    #pragma unroll
    for (int e = 0; e < 16; ++e) { acc0[e] = 0.f; acc1[e] = 0.f; }
    #pragma unroll
    for (int kc = 0; kc < 16; ++kc) {
      const short8 a0 = *(const short8*)&Abuf[kc*512 + l*8];
      acc0 = __builtin_amdgcn_mfma_f32_32x32x16_bf16(a0, breg0[kc], acc0, 0, 0, 0);
      acc1 = __builtin_amdgcn_mfma_f32_32x32x16_bf16(a0, breg1[kc], acc1, 0, 0, 0);
    }
    w_lgkm();
    s_bar();
    if (iter + 2 < 16) {
      const ushort* __restrict__ src = gAn + (size_t)(iter + 2)*8192;
      ushort* __restrict__ dstl = &Ab[iter & 1][0];
      #pragma unroll
      for (int i = 0; i < 4; ++i)
        glds16(src + (size_t)(i*256 + t)*8, dstl + (i*256 + t)*8);
    }

    #pragma unroll
    for (int r = 0; r < 16; ++r) {
      ws0 += __expf(fmaf(bq0, acc0[r], aq0));
      ws1 += __expf(fmaf(bq1, acc1[r], aq1));
    }
  }

  ws0 += __shfl_xor(ws0, 32, 64);
  ws1 += __shfl_xor(ws1, 32, 64);
  if (l < 32) {
    red2[w*32 + ln31]       = ws0;
    red2[128 + w*32 + ln31] = ws1;
  }
  __syncthreads();
  ws[OFF_WSUM + h*(NB*HW) + n*HW + col0 + t] = red2[t];
}

__global__ __launch_bounds__(256, 2) void k_gC(
    const ushort* __restrict__ gA, const ushort* __restrict__ gB,
    float* __restrict__ ws)
{
  __shared__ ushort Ab[2][8192];
  __shared__ float gam_s[256], bet_s[256];
  __shared__ float stash[4][512];

  const int t = threadIdx.x;
  const int w = t >> 6, l = t & 63;
  const int ln31 = l & 31, lhi = l >> 5;

  const int L = blockIdx.x;
  const int xcd = L & 7, g = L >> 3;
  const int nh = xcd*4 + (g & 3);
  const int cs = g >> 2;
  const int n = nh >> 3, h = nh & 7;
  const int col0 = cs * 256;

  const ushort* __restrict__ gAn = gA + ((size_t)(n*128 + h*16) << 13);

  #pragma unroll
  for (int i = 0; i < 4; ++i)
    glds16(gAn + (size_t)(i*256 + t)*8, &Ab[0][(i*256 + t)*8]);
  #pragma unroll
  for (int i = 0; i < 4; ++i)
    glds16(gAn + 8192 + (size_t)(i*256 + t)*8, &Ab[1][(i*256 + t)*8]);

  {
    const int idx = n*HW + col0 + t;
    float cm = -3.0e38f;
    #pragma unroll
    for (int hh = 0; hh < NQ0; ++hh)
      cm = fmaxf(cm, ws[OFF_CMAX + hh*(NB*HW) + idx]);
    float sw = 0.f;
    #pragma unroll
    for (int hh = 0; hh < NQ0; ++hh)
      sw += ws[OFF_WSUM + hh*(NB*HW) + idx];
    const float i0 = 1.0f/(2.0f*(0.5f*(1.0f - cm) + kEPS));
    bet_s[t] = i0 / kSIG;
    gam_s[t] = (1.0f - i0) / kSIG - logf(sw + kEPS);
  }

  short8 breg0[16], breg1[16];
  {
    const int RB0 = cs*8 + w, RB1 = cs*8 + 4 + w;
    #pragma unroll
    for (int kc = 0; kc < 16; ++kc) {
      breg0[kc] = *(const short8*)(gB + (((size_t)(n*128 + RB0)*16 + kc) << 9) + l*8);
      breg1[kc] = *(const short8*)(gB + (((size_t)(n*128 + RB1)*16 + kc) << 9) + l*8);
    }
  }
  __syncthreads();

  for (int iter = 0; iter < 16; ++iter) {
    if (iter < 15) w_vm4(); else w_vm0();
    s_bar();

    const ushort* __restrict__ Abuf = &Ab[iter & 1][0];
    f32x16 accq0, accq1;
    #pragma unroll
    for (int e = 0; e < 16; ++e) { accq0[e] = 0.f; accq1[e] = 0.f; }
    #pragma unroll
    for (int kc = 0; kc < 16; ++kc) {
      const short8 a0 = *(const short8*)&Abuf[kc*512 + l*8];
      accq0 = __builtin_amdgcn_mfma_f32_32x32x16_bf16(breg0[kc], a0, accq0, 0, 0, 0);
      accq1 = __builtin_amdgcn_mfma_f32_32x32x16_bf16(breg1[kc], a0, accq1, 0, 0, 0);
    }
    w_lgkm();
    s_bar();
    if (iter + 2 < 16) {
      const ushort* __restrict__ src = gAn + (size_t)(iter + 2)*8192;
      ushort* __restrict__ dstl = &Ab[iter & 1][0];
      #pragma unroll
      for (int i = 0; i < 4; ++i)
        glds16(src + (size_t)(i*256 + t)*8, dstl + (i*256 + t)*8);
    }

    float m = -3.0e38f;
    #pragma unroll
    for (int r = 0; r < 16; ++r) {
      const int row = (r & 3) + 8*(r >> 2) + 4*lhi;
      const float g0v = gam_s[w*32 + row],       b0v = bet_s[w*32 + row];
      const float g1v = gam_s[128 + w*32 + row], b1v = bet_s[128 + w*32 + row];
      m = fmaxf(m, fmaf(b0v, accq0[r], g0v));
      m = fmaxf(m, fmaf(b1v, accq1[r], g1v));
    }
    m = fmaxf(m, __shfl_xor(m, 32, 64));
    if (l < 32) stash[w][iter*32 + ln31] = m;
  }

  __syncthreads();
  unsigned* __restrict__ MV = (unsigned*)(ws + OFF_MAXV) + n*HW + h*512;
  #pragma unroll
  for (int p = t; p < 512; p += 256) {
    const float m = fmaxf(fmaxf(stash[0][p], stash[1][p]),
                          fmaxf(stash[2][p], stash[3][p]));
    atomicMax(&MV[p], enc_f32(m));
  }
}

__global__ __launch_bounds__(256) void k_final9(const float* __restrict__ ws,
                                                float* __restrict__ out) {
  const int t = threadIdx.x;
  const unsigned* __restrict__ MV = (const unsigned*)(ws + OFF_MAXV);
  float loss = 0.f;
  for (int n = 0; n < NB; ++n) {
    float s = 0.f;
    for (int k = 0; k < 16; ++k)
      s += __expf(dec_f32(MV[n*HW + k*256 + t]));
    const float tot = blockSum256(s);
    loss += -logf(tot*(1.0f/4096.0f) + kEPS);
  }
  if (t == 0) out[0] = loss*0.25f;
}

extern "C" void kernel_launch(void* const* d_in, const int* in_sizes, int n_in,
                              void* d_out, int out_size, void* d_ws, size_t ws_size,
                              hipStream_t stream) {
  const float* fT = (const float*)d_in[0];
  const float* fI = (const float*)d_in[1];
  float* out = (float*)d_out;
  float* ws  = (float*)d_ws;

  const size_t need_full = (size_t)WS_FLOATS_FULL * sizeof(float);
  if (ws_size < need_full) return;  // ~18 MB

  // preferred: single cooperative kernel (eliminates 5 launch gaps)
  {
    void* args[] = {(void*)&fT, (void*)&fI, (void*)&ws, (void*)&out};
    if (hipLaunchCooperativeKernel((const void*)k_all, dim3(512), dim3(256),
                                   args, 0, stream) == hipSuccess)
      return;
  }

  // fallback: proven R31 six-launch path
  const ushort* GT = (const ushort*)(ws + OFF_GT);
  const ushort* GI = (const ushort*)(ws + OFF_GI);
  k_mean9 <<<256,  256, 0, stream>>>(fT, ws);
  k_prep9 <<<1024, 256, 0, stream>>>(fT, fI, ws);
  k_gA    <<<512,  256, 0, stream>>>(GT, GI, ws);
  k_gB    <<<512,  256, 0, stream>>>(GT, GI, ws);
  k_gC    <<<512,  256, 0, stream>>>(GT, GI, ws);
  k_final9<<<1,    256, 0, stream>>>(ws, out);
}

// Round 15
// 174.424 us; speedup vs baseline: 2.4859x; 2.4859x over previous
//
#include <hip/hip_runtime.h>
#include <cmath>

// CXLoss pipeline, revision 33 == R31 restored verbatim (measured best:
// 171.8us, absmax 0.0). R32's cooperative fusion was decisively refuted:
// grid.sync ~45us each on a 512-block grid (k_all = 378us vs ~147us of
// phase work) -- the cooperative barrier is ~10x the launch gap it would
// replace. Search ledger now closed: staging structures (7), tile shapes
// (K_A/K_B), barrier counts, setprio, S-materialization vs recompute,
// epilogue transposes, launch-count reduction (k_red->atomicMax fold =
// kept win), cooperative fusion (loss). R31 is the empirical optimum:
// mean -> prep(+MAXV init) -> gA -> gB -> gC(atomicMax) -> final.

#define NB 4
#define CC 256
#define HW 4096
#define NQ0 8    // p-slab loop-split (CMAX/WSUM partials)

static constexpr float kEPS = 1e-8f;
static constexpr float kSIG = 0.1f + 1e-8f;

typedef __attribute__((ext_vector_type(8)))  short short8;
typedef __attribute__((ext_vector_type(16))) float f32x16;

// workspace layout (float units)
enum {
  OFF_MEAN = 0,                        // 256 channel means
  OFF_CMAX = 256,                      // NQ0*NB*HW colmax partials
  OFF_WSUM = OFF_CMAX + NQ0*NB*HW,     // NQ0*NB*HW Wsum partials
  OFF_MAXV = OFF_WSUM + NQ0*NB*HW,     // NB*HW maxv (ENCODED uint, atomicMax)
  OFF_GT   = OFF_MAXV + NB*HW,         // NB*HW*CC bf16, fragment-tiled
  OFF_GI   = OFF_GT + NB*HW*CC/2,
  WS_FLOATS_FULL = OFF_GI + NB*HW*CC/2
};

static constexpr unsigned kEncNegInf = 0x007fffffu;  // enc(-inf)

__device__ __forceinline__ unsigned enc_f32(float f) {
  const unsigned u = __float_as_uint(f);
  return (u & 0x80000000u) ? ~u : (u | 0x80000000u);
}
__device__ __forceinline__ float dec_f32(unsigned e) {
  const unsigned u = (e & 0x80000000u) ? (e & 0x7fffffffu) : ~e;
  return __uint_as_float(u);
}

__device__ __forceinline__ ushort cvt_bf16(float x) {
  unsigned u = __float_as_uint(x);
  unsigned r = (u + 0x7fffu + ((u >> 16) & 1u)) >> 16;  // round-nearest-even
  return (ushort)r;
}

__device__ __forceinline__ void glds16(const ushort* g, ushort* l) {
  __builtin_amdgcn_global_load_lds(
      (const __attribute__((address_space(1))) unsigned*)g,
      (__attribute__((address_space(3))) unsigned*)l, 16, 0, 0);
}
__device__ __forceinline__ void s_bar()  { asm volatile("s_barrier" ::: "memory"); }
__device__ __forceinline__ void w_vm4()  { asm volatile("s_waitcnt vmcnt(4)" ::: "memory"); }
__device__ __forceinline__ void w_vm0()  { asm volatile("s_waitcnt vmcnt(0)" ::: "memory"); }
__device__ __forceinline__ void w_lgkm() { asm volatile("s_waitcnt lgkmcnt(0)" ::: "memory"); }

__device__ __forceinline__ float blockSum256(float v) {
  __shared__ float sh[4];
  const int lane = threadIdx.x & 63, wv = threadIdx.x >> 6;
  #pragma unroll
  for (int o = 32; o > 0; o >>= 1) v += __shfl_down(v, o, 64);
  __syncthreads();
  if (lane == 0) sh[wv] = v;
  __syncthreads();
  return sh[0] + sh[1] + sh[2] + sh[3];
}

// K1: per-channel mean of featureT. grid=256
__global__ __launch_bounds__(256) void k_mean9(const float* __restrict__ fT,
                                               float* __restrict__ ws) {
  const int c = blockIdx.x, t = threadIdx.x;
  float s = 0.f;
  for (int n = 0; n < NB; ++n) {
    const float* p = fT + (size_t)(n*CC + c)*HW;
    #pragma unroll
    for (int k = 0; k < 16; ++k) s += p[k*256 + t];
  }
  const float tot = blockSum256(s);
  if (t == 0) ws[OFF_MEAN + c] = tot * (1.0f/16384.0f);
}

// K2: fused normalize + fragment-tiled bf16 write (verified R14 layout):
// offset_ushort(n, r32, kc) = ((n*128 + r32)*16 + kc)*512 + l*8
//   holds X[n][p = r32*32 + (l&31)][c = kc*16 + (l>>5)*8 + j], j<8.
// grid = 2 * NB * 128 = 1024 blocks. Blocks 0..63 also init MAXV=enc(-inf).
__global__ __launch_bounds__(256) void k_prep9(const float* __restrict__ fT,
                                               const float* __restrict__ fI,
                                               float* __restrict__ ws) {
  __shared__ float stage[32][257];
  __shared__ float prt[8][32];
  __shared__ float sinv[32];
  const int t = threadIdx.x, l = t & 63;
  const int obid = blockIdx.x;
  int bid = obid;
  const int tensor = (bid >= 512); bid &= 511;
  const int n   = bid >> 7;
  const int r32 = bid & 127;
  const int p0  = r32 * 32;

  if (obid < 64)   // init encoded MAXV (runs before k_gC in stream order)
    ((unsigned*)(ws + OFF_MAXV))[obid*256 + t] = kEncNegInf;

  const float* __restrict__ src = tensor ? fI : fT;
  ushort* __restrict__ dst = (ushort*)(ws + (tensor ? OFF_GI : OFF_GT));
  const float* __restrict__ mean = ws + OFF_MEAN;

  const int pl = t & 31, cg = t >> 5;
  float acc = 0.f;
  #pragma unroll
  for (int i = 0; i < 32; ++i) {
    const int c = cg*32 + i;
    const float v = src[((size_t)(n*CC + c))*HW + p0 + pl] - mean[c];
    stage[pl][c] = v;
    acc += v*v;
  }
  prt[cg][pl] = acc;
  __syncthreads();
  if (t < 32) {
    float s = 0.f;
    #pragma unroll
    for (int g = 0; g < 8; ++g) s += prt[g][t];
    sinv[t] = 1.0f/(sqrtf(s) + kEPS);
  }
  __syncthreads();

  const int w = t >> 6, lhi = l >> 5, m = l & 31;
  const float iv = sinv[m];
  #pragma unroll
  for (int i = 0; i < 4; ++i) {
    const int kc = w*4 + i;
    const int cb = kc*16 + lhi*8;
    short8 o;
    #pragma unroll
    for (int j = 0; j < 8; ++j)
      ((ushort*)&o)[j] = cvt_bf16(stage[m][cb + j] * iv);
    *(short8*)(dst + (((size_t)(n*128 + r32)*16 + kc) << 9) + l*8) = o;
  }
}

// ---- shared sweep geometry (K_B=2, glds + counted vmcnt) ----
// L: xcd = L&7, g = L>>3; nh = xcd*4 + (g&3); cs = g>>2.
// n = nh>>3, h = nh&7, col0 = cs*256.
// wave w: B col-tiles RB0 = cs*8+w, RB1 = cs*8+4+w; lane q0 = col0+w*32+ln31,
// q1 = q0+128. Per iter: glds tile -> Ab[iter&1]; 16 kc: 1 ds_read -> 2 MFMA.
// C/D map: col = lane&31, row = (r&3) + 8*(r>>2) + 4*(lane>>5).

// K3a: GEMM sweep + colmax partials. grid 512.
__global__ __launch_bounds__(256, 2) void k_gA(
    const ushort* __restrict__ gA, const ushort* __restrict__ gB,
    float* __restrict__ ws)
{
  __shared__ ushort Ab[2][8192];
  __shared__ float red2[256];

  const int t = threadIdx.x;
  const int w = t >> 6, l = t & 63;
  const int ln31 = l & 31;

  const int L = blockIdx.x;
  const int xcd = L & 7, g = L >> 3;
  const int nh = xcd*4 + (g & 3);
  const int cs = g >> 2;
  const int n = nh >> 3, h = nh & 7;
  const int col0 = cs * 256;

  const ushort* __restrict__ gAn = gA + ((size_t)(n*128 + h*16) << 13);

  // prologue: async-stage tiles 0,1
  #pragma unroll
  for (int i = 0; i < 4; ++i)
    glds16(gAn + (size_t)(i*256 + t)*8, &Ab[0][(i*256 + t)*8]);
  #pragma unroll
  for (int i = 0; i < 4; ++i)
    glds16(gAn + 8192 + (size_t)(i*256 + t)*8, &Ab[1][(i*256 + t)*8]);

  short8 breg0[16], breg1[16];
  {
    const int RB0 = cs*8 + w, RB1 = cs*8 + 4 + w;
    #pragma unroll
    for (int kc = 0; kc < 16; ++kc) {
      breg0[kc] = *(const short8*)(gB + (((size_t)(n*128 + RB0)*16 + kc) << 9) + l*8);
      breg1[kc] = *(const short8*)(gB + (((size_t)(n*128 + RB1)*16 + kc) << 9) + l*8);
    }
  }

  float run0 = -3.0e38f, run1 = -3.0e38f;

  for (int iter = 0; iter < 16; ++iter) {
    if (iter < 15) w_vm4(); else w_vm0();
    s_bar();                                   // Ab[iter&1] staged (all waves)

    const ushort* __restrict__ Abuf = &Ab[iter & 1][0];
    f32x16 acc0, acc1;
    #pragma unroll
    for (int e = 0; e < 16; ++e) { acc0[e] = 0.f; acc1[e] = 0.f; }
    #pragma unroll
    for (int kc = 0; kc < 16; ++kc) {
      const short8 a0 = *(const short8*)&Abuf[kc*512 + l*8];
      acc0 = __builtin_amdgcn_mfma_f32_32x32x16_bf16(a0, breg0[kc], acc0, 0, 0, 0);
      acc1 = __builtin_amdgcn_mfma_f32_32x32x16_bf16(a0, breg1[kc], acc1, 0, 0, 0);
    }
    w_lgkm();
    s_bar();                                   // all waves done reading Ab[iter&1]
    if (iter + 2 < 16) {
      const ushort* __restrict__ src = gAn + (size_t)(iter + 2)*8192;
      ushort* __restrict__ dstl = &Ab[iter & 1][0];
      #pragma unroll
      for (int i = 0; i < 4; ++i)
        glds16(src + (size_t)(i*256 + t)*8, dstl + (i*256 + t)*8);
    }

    #pragma unroll
    for (int r = 0; r < 16; ++r) {
      run0 = fmaxf(run0, acc0[r]);
      run1 = fmaxf(run1, acc1[r]);
    }
  }

  run0 = fmaxf(run0, __shfl_xor(run0, 32, 64));
  run1 = fmaxf(run1, __shfl_xor(run1, 32, 64));
  if (l < 32) {
    red2[w*32 + ln31]       = run0;
    red2[128 + w*32 + ln31] = run1;
  }
  __syncthreads();
  ws[OFF_CMAX + h*(NB*HW) + n*HW + col0 + t] = red2[t];
}

// K3b: GEMM sweep + Wsum partials. Per-lane a,b derived from CMAX.
__global__ __launch_bounds__(256, 2) void k_gB(
    const ushort* __restrict__ gA, const ushort* __restrict__ gB,
    float* __restrict__ ws)
{
  __shared__ ushort Ab[2][8192];
  __shared__ float red2[256];

  const int t = threadIdx.x;
  const int w = t >> 6, l = t & 63;
  const int ln31 = l & 31;

  const int L = blockIdx.x;
  const int xcd = L & 7, g = L >> 3;
  const int nh = xcd*4 + (g & 3);
  const int cs = g >> 2;
  const int n = nh >> 3, h = nh & 7;
  const int col0 = cs * 256;

  const ushort* __restrict__ gAn = gA + ((size_t)(n*128 + h*16) << 13);

  #pragma unroll
  for (int i = 0; i < 4; ++i)
    glds16(gAn + (size_t)(i*256 + t)*8, &Ab[0][(i*256 + t)*8]);
  #pragma unroll
  for (int i = 0; i < 4; ++i)
    glds16(gAn + 8192 + (size_t)(i*256 + t)*8, &Ab[1][(i*256 + t)*8]);

  // per-lane affine coeffs for both q columns (same op order as R24)
  float aq0, bq0, aq1, bq1;
  {
    const int q0 = col0 + w*32 + ln31;
    const int q1 = q0 + 128;
    float cm0 = -3.0e38f, cm1 = -3.0e38f;
    #pragma unroll
    for (int hh = 0; hh < NQ0; ++hh) {
      cm0 = fmaxf(cm0, ws[OFF_CMAX + hh*(NB*HW) + n*HW + q0]);
      cm1 = fmaxf(cm1, ws[OFF_CMAX + hh*(NB*HW) + n*HW + q1]);
    }
    const float i0 = 1.0f/(2.0f*(0.5f*(1.0f - cm0) + kEPS));
    const float i1 = 1.0f/(2.0f*(0.5f*(1.0f - cm1) + kEPS));
    bq0 = i0 / kSIG; aq0 = (1.0f - i0) / kSIG;
    bq1 = i1 / kSIG; aq1 = (1.0f - i1) / kSIG;
  }

  short8 breg0[16], breg1[16];
  {
    const int RB0 = cs*8 + w, RB1 = cs*8 + 4 + w;
    #pragma unroll
    for (int kc = 0; kc < 16; ++kc) {
      breg0[kc] = *(const short8*)(gB + (((size_t)(n*128 + RB0)*16 + kc) << 9) + l*8);
      breg1[kc] = *(const short8*)(gB + (((size_t)(n*128 + RB1)*16 + kc) << 9) + l*8);
    }
  }

  float ws0 = 0.f, ws1 = 0.f;

  for (int iter = 0; iter < 16; ++iter) {
    if (iter < 15) w_vm4(); else w_vm0();
    s_bar();

    const ushort* __restrict__ Abuf = &Ab[iter & 1][0];
    f32x16 acc0, acc1;
    #pragma unroll
    for (int e = 0; e < 16; ++e) { acc0[e] = 0.f; acc1[e] = 0.f; }
    #pragma unroll
    for (int kc = 0; kc < 16; ++kc) {
      const short8 a0 = *(const short8*)&Abuf[kc*512 + l*8];
      acc0 = __builtin_amdgcn_mfma_f32_32x32x16_bf16(a0, breg0[kc], acc0, 0, 0, 0);
      acc1 = __builtin_amdgcn_mfma_f32_32x32x16_bf16(a0, breg1[kc], acc1, 0, 0, 0);
    }
    w_lgkm();
    s_bar();
    if (iter + 2 < 16) {
      const ushort* __restrict__ src = gAn + (size_t)(iter + 2)*8192;
      ushort* __restrict__ dstl = &Ab[iter & 1][0];
      #pragma unroll
      for (int i = 0; i < 4; ++i)
        glds16(src + (size_t)(i*256 + t)*8, dstl + (i*256 + t)*8);
    }

    #pragma unroll
    for (int r = 0; r < 16; ++r) {
      ws0 += __expf(fmaf(bq0, acc0[r], aq0));
      ws1 += __expf(fmaf(bq1, acc1[r], aq1));
    }
  }

  ws0 += __shfl_xor(ws0, 32, 64);
  ws1 += __shfl_xor(ws1, 32, 64);
  if (l < 32) {
    red2[w*32 + ln31]       = ws0;
    red2[128 + w*32 + ln31] = ws1;
  }
  __syncthreads();
  ws[OFF_WSUM + h*(NB*HW) + n*HW + col0 + t] = red2[t];
}

// K3c: GEMM sweep + row-max (maxv), SWAPPED operands (R27 scheme):
// acc = mfma(breg, afrag) -> col(lane&31) = p, reg = q. Max over q is an
// in-register fmax chain + one shfl_xor(32). gamma/beta per q-row from a
// per-block LDS table. Strip maxima combined into MAXV via encoded
// atomicMax (fmax exact-assoc -> order-independent).
__global__ __launch_bounds__(256, 2) void k_gC(
    const ushort* __restrict__ gA, const ushort* __restrict__ gB,
    float* __restrict__ ws)
{
  __shared__ ushort Ab[2][8192];
  __shared__ float gam_s[256], bet_s[256];
  __shared__ float stash[4][512];   // 8KB: per-wave p-maxima

  const int t = threadIdx.x;
  const int w = t >> 6, l = t & 63;
  const int ln31 = l & 31, lhi = l >> 5;

  const int L = blockIdx.x;
  const int xcd = L & 7, g = L >> 3;
  const int nh = xcd*4 + (g & 3);
  const int cs = g >> 2;
  const int n = nh >> 3, h = nh & 7;
  const int col0 = cs * 256;

  const ushort* __restrict__ gAn = gA + ((size_t)(n*128 + h*16) << 13);

  #pragma unroll
  for (int i = 0; i < 4; ++i)
    glds16(gAn + (size_t)(i*256 + t)*8, &Ab[0][(i*256 + t)*8]);
  #pragma unroll
  for (int i = 0; i < 4; ++i)
    glds16(gAn + 8192 + (size_t)(i*256 + t)*8, &Ab[1][(i*256 + t)*8]);

  // gamma/beta table for this block's 256 q (formula/order == old k_gb9)
  {
    const int idx = n*HW + col0 + t;
    float cm = -3.0e38f;
    #pragma unroll
    for (int hh = 0; hh < NQ0; ++hh)
      cm = fmaxf(cm, ws[OFF_CMAX + hh*(NB*HW) + idx]);
    float sw = 0.f;
    #pragma unroll
    for (int hh = 0; hh < NQ0; ++hh)
      sw += ws[OFF_WSUM + hh*(NB*HW) + idx];
    const float i0 = 1.0f/(2.0f*(0.5f*(1.0f - cm) + kEPS));
    bet_s[t] = i0 / kSIG;
    gam_s[t] = (1.0f - i0) / kSIG - logf(sw + kEPS);
  }

  short8 breg0[16], breg1[16];
  {
    const int RB0 = cs*8 + w, RB1 = cs*8 + 4 + w;
    #pragma unroll
    for (int kc = 0; kc < 16; ++kc) {
      breg0[kc] = *(const short8*)(gB + (((size_t)(n*128 + RB0)*16 + kc) << 9) + l*8);
      breg1[kc] = *(const short8*)(gB + (((size_t)(n*128 + RB1)*16 + kc) << 9) + l*8);
    }
  }
  __syncthreads();   // gam/bet table ready (also covers stash init ordering)

  for (int iter = 0; iter < 16; ++iter) {
    if (iter < 15) w_vm4(); else w_vm0();
    s_bar();                                   // Ab[iter&1] staged

    const ushort* __restrict__ Abuf = &Ab[iter & 1][0];
    f32x16 accq0, accq1;                       // rows = q, cols = p (swapped)
    #pragma unroll
    for (int e = 0; e < 16; ++e) { accq0[e] = 0.f; accq1[e] = 0.f; }
    #pragma unroll
    for (int kc = 0; kc < 16; ++kc) {
      const short8 a0 = *(const short8*)&Abuf[kc*512 + l*8];
      accq0 = __builtin_amdgcn_mfma_f32_32x32x16_bf16(breg0[kc], a0, accq0, 0, 0, 0);
      accq1 = __builtin_amdgcn_mfma_f32_32x32x16_bf16(breg1[kc], a0, accq1, 0, 0, 0);
    }
    w_lgkm();
    s_bar();
    if (iter + 2 < 16) {
      const ushort* __restrict__ src = gAn + (size_t)(iter + 2)*8192;
      ushort* __restrict__ dstl = &Ab[iter & 1][0];
      #pragma unroll
      for (int i = 0; i < 4; ++i)
        glds16(src + (size_t)(i*256 + t)*8, dstl + (i*256 + t)*8);
    }

    // epilogue: lane holds p = iter*32 + ln31; 16 q-rows per acc tile.
    float m = -3.0e38f;
    #pragma unroll
    for (int r = 0; r < 16; ++r) {
      const int row = (r & 3) + 8*(r >> 2) + 4*lhi;
      const float g0v = gam_s[w*32 + row],       b0v = bet_s[w*32 + row];
      const float g1v = gam_s[128 + w*32 + row], b1v = bet_s[128 + w*32 + row];
      m = fmaxf(m, fmaf(b0v, accq0[r], g0v));
      m = fmaxf(m, fmaf(b1v, accq1[r], g1v));
    }
    m = fmaxf(m, __shfl_xor(m, 32, 64));       // merge lhi q-halves
    if (l < 32) stash[w][iter*32 + ln31] = m;  // p-local = iter*32 + ln31
  }

  __syncthreads();
  unsigned* __restrict__ MV = (unsigned*)(ws + OFF_MAXV) + n*HW + h*512;
  #pragma unroll
  for (int p = t; p < 512; p += 256) {
    const float m = fmaxf(fmaxf(stash[0][p], stash[1][p]),
                          fmaxf(stash[2][p], stash[3][p]));
    atomicMax(&MV[p], enc_f32(m));
  }
}

// K7: final loss. one block. Decodes MAXV.
__global__ __launch_bounds__(256) void k_final9(const float* __restrict__ ws,
                                                float* __restrict__ out) {
  const int t = threadIdx.x;
  const unsigned* __restrict__ MV = (const unsigned*)(ws + OFF_MAXV);
  float loss = 0.f;
  for (int n = 0; n < NB; ++n) {
    float s = 0.f;
    for (int k = 0; k < 16; ++k)
      s += __expf(dec_f32(MV[n*HW + k*256 + t]));
    const float tot = blockSum256(s);
    loss += -logf(tot*(1.0f/4096.0f) + kEPS);
  }
  if (t == 0) out[0] = loss*0.25f;
}

extern "C" void kernel_launch(void* const* d_in, const int* in_sizes, int n_in,
                              void* d_out, int out_size, void* d_ws, size_t ws_size,
                              hipStream_t stream) {
  const float* fT = (const float*)d_in[0];
  const float* fI = (const float*)d_in[1];
  float* out = (float*)d_out;
  float* ws  = (float*)d_ws;

  const size_t need_full = (size_t)WS_FLOATS_FULL * sizeof(float);
  if (ws_size < need_full) return;  // ~18 MB

  const ushort* GT = (const ushort*)(ws + OFF_GT);
  const ushort* GI = (const ushort*)(ws + OFF_GI);
  k_mean9 <<<256,  256, 0, stream>>>(fT, ws);
  k_prep9 <<<1024, 256, 0, stream>>>(fT, fI, ws);   // + MAXV init
  k_gA    <<<512,  256, 0, stream>>>(GT, GI, ws);   // colmax partials
  k_gB    <<<512,  256, 0, stream>>>(GT, GI, ws);   // Wsum partials
  k_gC    <<<512,  256, 0, stream>>>(GT, GI, ws);   // maxv via atomicMax
  k_final9<<<1,    256, 0, stream>>>(ws, out);
}